// Round 6
// baseline (202.813 us; speedup 1.0000x reference)
//
#include <hip/hip_runtime.h>

#define N_FEAT 128
#define HID 16
#define NPB 128          // nodes per fine bucket (7-bit local dst)
#define KMAX 1024        // max fine buckets (K = 782 here)
#define SEGCAP 8192      // max edges per fine bucket in sort LDS
#define EPT 16           // edges per thread in binning kernels
#define CMAXP1 17        // max coarse buckets + 1 (coarse = 8192 nodes)

// ctrl region (ints): bcnt@0(1024) | bstart@1024(1056) | gcursorF@2080(1024)
//                     | cstart@3104(24) | gcursorC@3128(24)   (<= 3584 total)
#define CTRL_INTS 3584

// ================= fine histogram (dst>>7) ================================
__global__ void bhist_kernel(const int* __restrict__ dst,
                             int* __restrict__ bcnt, int E, int K) {
    __shared__ int h[KMAX];
    for (int i = threadIdx.x; i < KMAX; i += 256) h[i] = 0;
    __syncthreads();
    for (long long e = (long long)blockIdx.x * 256 + threadIdx.x; e < E;
         e += (long long)gridDim.x * 256)
        atomicAdd(&h[dst[e] >> 7], 1);
    __syncthreads();
    for (int i = threadIdx.x; i < K; i += 256)
        if (h[i]) atomicAdd(&bcnt[i], h[i]);
}

// ================= scan: fine starts + coarse starts ======================
__global__ void bscan_kernel(const int* __restrict__ bcnt,
                             int* __restrict__ bstart,
                             int* __restrict__ gcursorF,
                             int* __restrict__ cstart,
                             int* __restrict__ gcursorC, int K, int E) {
    __shared__ int l[KMAX];
    int t = threadIdx.x;
    int v = (t < K) ? bcnt[t] : 0;
    l[t] = v;
    __syncthreads();
    for (int off = 1; off < KMAX; off <<= 1) {
        int tmp = (t >= off) ? l[t - off] : 0;
        __syncthreads();
        l[t] += tmp;
        __syncthreads();
    }
    int excl = l[t] - v;
    bstart[t]   = excl;          // == E for t >= K
    gcursorF[t] = excl;
    if ((t & 63) == 0) {         // coarse c = t>>6 starts at fine t
        cstart[t >> 6]   = excl;
        gcursorC[t >> 6] = excl;
    }
    if (t == 0) { bstart[KMAX] = E; cstart[16] = E; }
}

// ================= pass A: partition into 13 coarse buckets ===============
__global__ void binA_kernel(const int* __restrict__ src,
                            const int* __restrict__ dst,
                            int* __restrict__ gcursorC,
                            int* __restrict__ binnedA, int E) {
    __shared__ int rcnt[16], rbase[16];
    int base = blockIdx.x * (256 * EPT);
    if (base >= E) return;
    if (threadIdx.x < 16) rcnt[threadIdx.x] = 0;
    __syncthreads();

    int myc[EPT], myoff[EPT], mypack[EPT];
#pragma unroll
    for (int q = 0; q < EPT; ++q) {
        int e = base + q * 256 + threadIdx.x;
        myc[q] = -1;
        if (e < E) {
            int d = dst[e], s = src[e];
            int c = d >> 13;
            myc[q]    = c;
            mypack[q] = ((d & 8191) << 17) | s;   // 13-bit local dst | src
            myoff[q]  = atomicAdd(&rcnt[c], 1);
        }
    }
    __syncthreads();
    if (threadIdx.x < 16) {
        int c = rcnt[threadIdx.x];
        if (c > 0) rbase[threadIdx.x] = atomicAdd(&gcursorC[threadIdx.x], c);
    }
    __syncthreads();
#pragma unroll
    for (int q = 0; q < EPT; ++q)
        if (myc[q] >= 0) binnedA[rbase[myc[q]] + myoff[q]] = mypack[q];
}

// ================= pass B: coarse -> fine (64 fine per coarse) ============
__global__ void binB_kernel(const int* __restrict__ binnedA,
                            const int* __restrict__ cstart,
                            int* __restrict__ gcursorF,
                            int* __restrict__ binned, int E) {
    __shared__ int rcnt[192], rbase[192];
    __shared__ int cs[CMAXP1];
    int base = blockIdx.x * (256 * EPT);
    if (base >= E) return;
    if (threadIdx.x < CMAXP1) cs[threadIdx.x] = cstart[threadIdx.x];
    for (int i = threadIdx.x; i < 192; i += 256) rcnt[i] = 0;
    __syncthreads();

    int c0 = 0;
    while (c0 < 15 && cs[c0 + 1] <= base) ++c0;   // uniform across block

    int myf[EPT], myoff[EPT], mypack[EPT];
#pragma unroll
    for (int q = 0; q < EPT; ++q) {
        int e = base + q * 256 + threadIdx.x;
        myf[q] = -1;
        if (e < E) {
            int p = binnedA[e];
            int dl13 = p >> 17;
            int c = c0;
            while (c < 15 && e >= cs[c + 1]) ++c;
            int fr = ((c - c0) << 6) + (dl13 >> 7);   // < 192 (<=2 coarse/slice)
            myf[q]    = fr;
            myoff[q]  = atomicAdd(&rcnt[fr], 1);
            mypack[q] = ((dl13 & 127) << 17) | (p & 0x1FFFF);
        }
    }
    __syncthreads();
    for (int i = threadIdx.x; i < 192; i += 256) {
        int c = rcnt[i];
        if (c > 0) rbase[i] = atomicAdd(&gcursorF[(c0 << 6) + i], c);
    }
    __syncthreads();
#pragma unroll
    for (int q = 0; q < EPT; ++q)
        if (myf[q] >= 0) binned[rbase[myf[q]] + myoff[q]] = mypack[q];
}

// ================= fallback: one-level binning (round-5, proven) ==========
__global__ void bin_kernel(const int* __restrict__ src,
                           const int* __restrict__ dst,
                           int* __restrict__ gcursor,
                           int* __restrict__ binned, int E) {
    __shared__ int rcnt[KMAX];
    __shared__ int rbase[KMAX];
    int base = blockIdx.x * (256 * EPT);
    if (base >= E) return;

    for (int i = threadIdx.x; i < KMAX; i += 256) rcnt[i] = 0;
    __syncthreads();

    int myb[EPT], myoff[EPT], mypack[EPT];
#pragma unroll
    for (int q = 0; q < EPT; ++q) {
        int e = base + q * 256 + threadIdx.x;
        myb[q] = -1;
        if (e < E) {
            int d = dst[e], s = src[e];
            int b = d >> 7;
            myb[q]    = b;
            mypack[q] = ((d & 127) << 17) | s;
            myoff[q]  = atomicAdd(&rcnt[b], 1);
        }
    }
    __syncthreads();
    for (int i = threadIdx.x; i < KMAX; i += 256) {
        int c = rcnt[i];
        if (c > 0) rbase[i] = atomicAdd(&gcursor[i], c);
    }
    __syncthreads();
#pragma unroll
    for (int q = 0; q < EPT; ++q)
        if (myb[q] >= 0) binned[rbase[myb[q]] + myoff[q]] = mypack[q];
}

// ===== per-fine-bucket counting sort (in place) + row_start + dinv ========
__global__ void sort_kernel(const int* __restrict__ bstart,
                            int* __restrict__ binned,
                            int* __restrict__ row_start,
                            float* __restrict__ dinv, int n, int E) {
    __shared__ int seg[SEGCAP];
    __shared__ int cnt[NPB];
    __shared__ int excl[NPB];
    __shared__ int cur[NPB];
    int b = blockIdx.x;
    int rs = bstart[b], re = bstart[b + 1];
    int m = re - rs;
    if (m > SEGCAP) m = SEGCAP;
    int t = threadIdx.x;

    if (t < NPB) cnt[t] = 0;
    __syncthreads();

    for (int k = t; k < m; k += 256) {
        int p = binned[rs + k];
        seg[k] = p;
        atomicAdd(&cnt[p >> 17], 1);
    }
    __syncthreads();

    if (t < NPB) excl[t] = cnt[t];
    __syncthreads();
    for (int off = 1; off < NPB; off <<= 1) {
        int v = (t < NPB && t >= off) ? excl[t - off] : 0;
        __syncthreads();
        if (t < NPB) excl[t] += v;
        __syncthreads();
    }

    int vbase = b * NPB;
    if (t < NPB) {
        int e0 = excl[t] - cnt[t];
        cur[t] = e0;
        int v = vbase + t;
        if (v < n) {
            row_start[v] = rs + e0;
            dinv[v] = rsqrtf((float)cnt[t] + 1.0f);
        }
    }
    if (b == 0 && t == 0) row_start[n] = E;
    __syncthreads();

    for (int k = t; k < m; k += 256) {
        int p = seg[k];
        int pos = rs + atomicAdd(&cur[p >> 17], 1);
        binned[pos] = p & 0x1FFFF;                 // sorted src
    }
}

// ================= xform1: g1 planes = (x @ W1) * dinv ====================
__global__ void xform1_kernel(const float* __restrict__ x,
                              const float* __restrict__ W1,
                              const float* __restrict__ dinv,
                              float* __restrict__ p0,
                              float* __restrict__ p1, int n) {
    __shared__ float Ws[N_FEAT * HID];
    for (int i = threadIdx.x; i < N_FEAT * HID; i += blockDim.x)
        Ws[i] = W1[i];
    __syncthreads();

    int v = blockIdx.x * blockDim.x + threadIdx.x;
    if (v >= n) return;

    float acc[HID];
#pragma unroll
    for (int j = 0; j < HID; ++j) acc[j] = 0.0f;

    const float4* xr = (const float4*)(x + (size_t)v * N_FEAT);
#pragma unroll
    for (int k4 = 0; k4 < N_FEAT / 4; ++k4) {
        float4 xv = xr[k4];
        int k = k4 * 4;
#pragma unroll
        for (int j = 0; j < HID; ++j) {
            acc[j] += xv.x * Ws[(k + 0) * HID + j]
                    + xv.y * Ws[(k + 1) * HID + j]
                    + xv.z * Ws[(k + 2) * HID + j]
                    + xv.w * Ws[(k + 3) * HID + j];
        }
    }
    float dv = dinv[v];
    float4* o0 = (float4*)(p0 + (size_t)v * 8);
    float4* o1 = (float4*)(p1 + (size_t)v * 8);
    float4 w;
    w.x = acc[0] * dv; w.y = acc[1] * dv; w.z = acc[2] * dv; w.w = acc[3] * dv;
    o0[0] = w;
    w.x = acc[4] * dv; w.y = acc[5] * dv; w.z = acc[6] * dv; w.w = acc[7] * dv;
    o0[1] = w;
    w.x = acc[8] * dv; w.y = acc[9] * dv; w.z = acc[10] * dv; w.w = acc[11] * dv;
    o1[0] = w;
    w.x = acc[12] * dv; w.y = acc[13] * dv; w.z = acc[14] * dv; w.w = acc[15] * dv;
    o1[1] = w;
}

// ================= layer-1 aggregation (raw plane sums) ===================
// plane = blockIdx.x & 1  -> XCDs (round-robin mod 8) each touch ONE plane
__global__ void agg_raw_kernel(const int* __restrict__ row_start,
                               const int* __restrict__ slots,
                               const float* __restrict__ g0,
                               const float* __restrict__ g1,
                               float* __restrict__ a0,
                               float* __restrict__ a1, int n) {
    int plane = blockIdx.x & 1;
    int nodeblk = blockIdx.x >> 1;
    const float* __restrict__ gp = plane ? g1 : g0;
    float* __restrict__ ap = plane ? a1 : a0;

    int v = nodeblk * 32 + (threadIdx.x >> 3);
    int j = threadIdx.x & 7;
    if (v >= n) return;

    int rs = row_start[v], re = row_start[v + 1];
    float s0 = 0.f, s1 = 0.f, s2 = 0.f, s3 = 0.f,
          s4 = 0.f, s5 = 0.f, s6 = 0.f, s7 = 0.f;
    int k = rs;
    for (; k + 8 <= re; k += 8) {
        int e0 = slots[k],     e1 = slots[k + 1], e2 = slots[k + 2], e3 = slots[k + 3];
        int e4 = slots[k + 4], e5 = slots[k + 5], e6 = slots[k + 6], e7 = slots[k + 7];
        s0 += gp[(size_t)e0 * 8 + j];
        s1 += gp[(size_t)e1 * 8 + j];
        s2 += gp[(size_t)e2 * 8 + j];
        s3 += gp[(size_t)e3 * 8 + j];
        s4 += gp[(size_t)e4 * 8 + j];
        s5 += gp[(size_t)e5 * 8 + j];
        s6 += gp[(size_t)e6 * 8 + j];
        s7 += gp[(size_t)e7 * 8 + j];
    }
    for (; k < re; ++k) s0 += gp[(size_t)slots[k] * 8 + j];
    ap[(size_t)v * 8 + j] = ((s0 + s1) + (s2 + s3)) + ((s4 + s5) + (s6 + s7));
}

// ====== fin1: t=relu(dv*(acc+g1)+b1); g2 = dv*(t@W2)  (in place over acc) ==
__global__ void fin1_kernel(float* __restrict__ a0,   // acc in / g2 out
                            float* __restrict__ a1,
                            const float* __restrict__ g0,
                            const float* __restrict__ g1,
                            const float* __restrict__ dinv,
                            const float* __restrict__ b1,
                            const float* __restrict__ W2, int n) {
    __shared__ float W2s[HID * HID];
    W2s[threadIdx.x] = W2[threadIdx.x];   // blockDim == 256
    __syncthreads();

    int v = blockIdx.x * 256 + threadIdx.x;
    if (v >= n) return;
    float dv = dinv[v];

    float t[HID];
    const float4* A0 = (const float4*)(a0 + (size_t)v * 8);
    const float4* A1 = (const float4*)(a1 + (size_t)v * 8);
    const float4* G0 = (const float4*)(g0 + (size_t)v * 8);
    const float4* G1 = (const float4*)(g1 + (size_t)v * 8);
#pragma unroll
    for (int q = 0; q < 2; ++q) {
        float4 av = A0[q], gv = G0[q];
        t[q * 4 + 0] = fmaxf(dv * (av.x + gv.x) + b1[q * 4 + 0], 0.0f);
        t[q * 4 + 1] = fmaxf(dv * (av.y + gv.y) + b1[q * 4 + 1], 0.0f);
        t[q * 4 + 2] = fmaxf(dv * (av.z + gv.z) + b1[q * 4 + 2], 0.0f);
        t[q * 4 + 3] = fmaxf(dv * (av.w + gv.w) + b1[q * 4 + 3], 0.0f);
    }
#pragma unroll
    for (int q = 0; q < 2; ++q) {
        float4 av = A1[q], gv = G1[q];
        t[8 + q * 4 + 0] = fmaxf(dv * (av.x + gv.x) + b1[8 + q * 4 + 0], 0.0f);
        t[8 + q * 4 + 1] = fmaxf(dv * (av.y + gv.y) + b1[8 + q * 4 + 1], 0.0f);
        t[8 + q * 4 + 2] = fmaxf(dv * (av.z + gv.z) + b1[8 + q * 4 + 2], 0.0f);
        t[8 + q * 4 + 3] = fmaxf(dv * (av.w + gv.w) + b1[8 + q * 4 + 3], 0.0f);
    }

    float h[HID];
#pragma unroll
    for (int j2 = 0; j2 < HID; ++j2) {
        float acc = 0.0f;
#pragma unroll
        for (int j = 0; j < HID; ++j) acc += t[j] * W2s[j * HID + j2];
        h[j2] = acc * dv;
    }
    float4* O0 = (float4*)(a0 + (size_t)v * 8);
    float4* O1 = (float4*)(a1 + (size_t)v * 8);
    float4 w;
    w.x = h[0];  w.y = h[1];  w.z = h[2];  w.w = h[3];  O0[0] = w;
    w.x = h[4];  w.y = h[5];  w.z = h[6];  w.w = h[7];  O0[1] = w;
    w.x = h[8];  w.y = h[9];  w.z = h[10]; w.w = h[11]; O1[0] = w;
    w.x = h[12]; w.y = h[13]; w.z = h[14]; w.w = h[15]; O1[1] = w;
}

// ================= layer-2 aggregation + finalize + bias ==================
__global__ void agg_fin_kernel(const int* __restrict__ row_start,
                               const int* __restrict__ slots,
                               const float* __restrict__ g0,
                               const float* __restrict__ g1,
                               const float* __restrict__ dinv,
                               const float* __restrict__ b2,
                               float* __restrict__ out, int n) {
    int plane = blockIdx.x & 1;
    int nodeblk = blockIdx.x >> 1;
    const float* __restrict__ gp = plane ? g1 : g0;

    int v = nodeblk * 32 + (threadIdx.x >> 3);
    int j = threadIdx.x & 7;
    if (v >= n) return;

    int rs = row_start[v], re = row_start[v + 1];
    float s0 = 0.f, s1 = 0.f, s2 = 0.f, s3 = 0.f,
          s4 = 0.f, s5 = 0.f, s6 = 0.f, s7 = 0.f;
    int k = rs;
    for (; k + 8 <= re; k += 8) {
        int e0 = slots[k],     e1 = slots[k + 1], e2 = slots[k + 2], e3 = slots[k + 3];
        int e4 = slots[k + 4], e5 = slots[k + 5], e6 = slots[k + 6], e7 = slots[k + 7];
        s0 += gp[(size_t)e0 * 8 + j];
        s1 += gp[(size_t)e1 * 8 + j];
        s2 += gp[(size_t)e2 * 8 + j];
        s3 += gp[(size_t)e3 * 8 + j];
        s4 += gp[(size_t)e4 * 8 + j];
        s5 += gp[(size_t)e5 * 8 + j];
        s6 += gp[(size_t)e6 * 8 + j];
        s7 += gp[(size_t)e7 * 8 + j];
    }
    for (; k < re; ++k) s0 += gp[(size_t)slots[k] * 8 + j];
    float acc = ((s0 + s1) + (s2 + s3)) + ((s4 + s5) + (s6 + s7));

    float dv = dinv[v];
    float self = gp[(size_t)v * 8 + j];
    out[(size_t)v * HID + plane * 8 + j] = dv * (acc + self) + b2[plane * 8 + j];
}

// ===========================================================================
extern "C" void kernel_launch(void* const* d_in, const int* in_sizes, int n_in,
                              void* d_out, int out_size, void* d_ws, size_t ws_size,
                              hipStream_t stream) {
    const float* x  = (const float*)d_in[0];
    const int*   ei = (const int*)d_in[1];     // int32 (JAX x64 disabled)
    const float* W1 = (const float*)d_in[2];
    const float* b1 = (const float*)d_in[3];
    const float* W2 = (const float*)d_in[4];
    const float* b2 = (const float*)d_in[5];
    float* out = (float*)d_out;

    const int n = in_sizes[0] / N_FEAT;         // 100000
    const int E = in_sizes[1] / 2;              // 3200000
    const int* src = ei;
    const int* dst = ei + E;

    const int B = 256;
    size_t nal = ((size_t)n + 255) & ~(size_t)255;
    const int K = (n + NPB - 1) / NPB;          // 782 fine buckets

    // Path A (two-level): binnedA(E) | binned(E) | ctrl | row_start(nal+64) |
    //                     dinv(nal) | g1p(16nal)        [g2p reuses binnedA]
    size_t needA = (2 * (size_t)E + CTRL_INTS + 18 * nal + 64) * sizeof(int);
    // Path B (one-level): binned(E) | ctrl | row_start(nal+64) | dinv(nal) |
    //                     g1p(16nal) | g2p(16nal)
    size_t needB = ((size_t)E + CTRL_INTS + 34 * nal + 64) * sizeof(int);

    bool pathA = (ws_size >= needA) && (K <= KMAX);

    int* binnedA;   // Path A only
    int* binned;
    int* ctrl;
    if (pathA) {
        binnedA = (int*)d_ws;
        binned  = binnedA + E;
        ctrl    = binned + E;
    } else {
        binnedA = nullptr;
        binned  = (int*)d_ws;
        ctrl    = binned + E;
    }
    int* bcnt     = ctrl;            // 1024
    int* bstart   = ctrl + 1024;     // 1056 (indices 0..KMAX)
    int* gcursorF = ctrl + 2080;     // 1024
    int* cstart   = ctrl + 3104;     // 24
    int* gcursorC = ctrl + 3128;     // 24
    int* row_start = ctrl + CTRL_INTS;               // nal + 64
    float* dinv    = (float*)(row_start + nal + 64); // nal
    float* g1p0    = dinv + nal;                     // 8*nal
    float* g1p1    = g1p0 + 8 * nal;                 // 8*nal
    float* g2p0, *g2p1;
    if (pathA) {
        g2p0 = (float*)binnedA;                      // reuse (free after binB)
        g2p1 = g2p0 + 8 * nal;
    } else {
        g2p0 = g1p1 + 8 * nal;
        g2p1 = g2p0 + 8 * nal;
    }

    hipMemsetAsync(bcnt, 0, 1024 * sizeof(int), stream);

    bhist_kernel<<<512, 256, 0, stream>>>(dst, bcnt, E, K);
    bscan_kernel<<<1, KMAX, 0, stream>>>(bcnt, bstart, gcursorF, cstart, gcursorC, K, E);

    int nblk = (E + 256 * EPT - 1) / (256 * EPT);
    if (pathA) {
        binA_kernel<<<nblk, 256, 0, stream>>>(src, dst, gcursorC, binnedA, E);
        binB_kernel<<<nblk, 256, 0, stream>>>(binnedA, cstart, gcursorF, binned, E);
    } else {
        bin_kernel<<<nblk, 256, 0, stream>>>(src, dst, gcursorF, binned, E);
    }

    sort_kernel<<<K, 256, 0, stream>>>(bstart, binned, row_start, dinv, n, E);

    xform1_kernel<<<(n + B - 1) / B, B, 0, stream>>>(x, W1, dinv, g1p0, g1p1, n);

    int nb32 = (n + 31) / 32;
    agg_raw_kernel<<<2 * nb32, 256, 0, stream>>>(row_start, binned,
                                                 g1p0, g1p1, g2p0, g2p1, n);
    fin1_kernel<<<(n + 255) / 256, 256, 0, stream>>>(g2p0, g2p1, g1p0, g1p1,
                                                     dinv, b1, W2, n);
    agg_fin_kernel<<<2 * nb32, 256, 0, stream>>>(row_start, binned,
                                                 g2p0, g2p1, dinv, b2, out, n);
}